// Round 3
// baseline (51.419 us; speedup 1.0000x reference)
//
#include <hip/hip_runtime.h>
#include <hip/hip_bf16.h>

// Problem constants (from reference setup_inputs):
//   x: [B=4, NC=2000, F=4, H=64] fp32
//   fine_to_coarse: [NF=50000] int32 in [0, NC)
//   out: [B=4, NF=50000, F=4, H=64] fp32
// Row size per (b, node) = F*H = 256 floats = 1024 B = 64 float4.
//
// Write-BW-bound: 204.8 MB out. Strategy: one wave = one nf row slot,
// each thread handles all 4 batches (shared index, 4 independent
// load->store chains, nontemporal stores).

#define B_  4
#define NC_ 2000
#define NF_ 50000
#define ROW_F4 64   // float4 elements per row (F*H/4)

// Native clang vector type — __builtin_nontemporal_store requires this
// (HIP's float4 is a class and is rejected).
typedef float vf4 __attribute__((ext_vector_type(4)));

__global__ __launch_bounds__(256) void unpool_gather_kernel(
    const vf4* __restrict__ x,      // [B, NC, 64] vf4
    const int* __restrict__ ftc,    // [NF]
    vf4*       __restrict__ out)    // [B, NF, 64] vf4
{
    const int idx = blockIdx.x * blockDim.x + threadIdx.x;  // over NF_*64
    const int nf    = idx >> 6;        // wave-uniform (64 lanes per row)
    const int inner = idx & 63;

    const int c = ftc[nf];             // broadcast load, shared by all 4 batches

    const vf4* src = x   + (size_t)c  * ROW_F4 + inner;
    vf4*       dst = out + (size_t)nf * ROW_F4 + inner;

    const size_t xb = (size_t)NC_ * ROW_F4;   // batch stride in x
    const size_t ob = (size_t)NF_ * ROW_F4;   // batch stride in out

    // Issue all 4 independent loads first (MLP), then 4 streaming stores.
    vf4 v0 = src[0 * xb];
    vf4 v1 = src[1 * xb];
    vf4 v2 = src[2 * xb];
    vf4 v3 = src[3 * xb];

    __builtin_nontemporal_store(v0, &dst[0 * ob]);
    __builtin_nontemporal_store(v1, &dst[1 * ob]);
    __builtin_nontemporal_store(v2, &dst[2 * ob]);
    __builtin_nontemporal_store(v3, &dst[3 * ob]);
}

extern "C" void kernel_launch(void* const* d_in, const int* in_sizes, int n_in,
                              void* d_out, int out_size, void* d_ws, size_t ws_size,
                              hipStream_t stream) {
    const vf4* x   = (const vf4*)d_in[0];
    const int* ftc = (const int*)d_in[1];
    vf4*       out = (vf4*)d_out;

    // NF_*64 vf4 slots; each thread covers all 4 batches for its slot.
    dim3 grid((NF_ * 64) / 256);
    dim3 block(256);
    unpool_gather_kernel<<<grid, block, 0, stream>>>(x, ftc, out);
}

// Round 4
// 50.424 us; speedup vs baseline: 1.0197x; 1.0197x over previous
//
#include <hip/hip_runtime.h>
#include <hip/hip_bf16.h>

// Problem constants (from reference setup_inputs):
//   x: [B=4, NC=2000, F=4, H=64] fp32          (8.2 MB  — L2/L3 resident)
//   fine_to_coarse: [NF=50000] int32 in [0,NC) (200 KB)
//   out: [B=4, NF=50000, F=4, H=64] fp32       (204.8 MB — write-BW bound)
// Row per (b,node) = F*H = 256 floats = 1 KB = 64 float4 = one wave-store.
//
// Strategy: persistent waves. 50000 rows = 2000 waves x 25 rows (exact).
// Each wave loops 25 consecutive nf rows, unroll 5 for deep MLP; batch via
// grid.y. Plain (cached) stores — NT stores regressed in round 3.

#define B_     4
#define NC_    2000
#define NF_    50000
#define ROW_F4 64
#define CHUNK  25          // nf rows per wave: 50000 = 2000 * 25
#define TPB    256         // 4 waves/block
#define BLOCKS_X 500       // 2000 waves / 4 per block

typedef float vf4 __attribute__((ext_vector_type(4)));

__global__ __launch_bounds__(TPB) void unpool_gather_kernel(
    const vf4* __restrict__ x,      // [B, NC, 64] vf4
    const int* __restrict__ ftc,    // [NF]
    vf4*       __restrict__ out)    // [B, NF, 64] vf4
{
    const int t    = blockIdx.x * TPB + threadIdx.x;
    const int wave = t >> 6;            // [0, 2000)
    const int lane = t & 63;
    const int b    = blockIdx.y;

    const int nf0 = wave * CHUNK;

    const vf4* __restrict__ xb = x + (size_t)b * NC_ * ROW_F4 + lane;
    vf4* __restrict__ ob = out + ((size_t)b * NF_ + nf0) * ROW_F4 + lane;

    #pragma unroll 5
    for (int i = 0; i < CHUNK; ++i) {
        // nf is wave-uniform; force it into an SGPR so the index fetch is a
        // scalar load (frees the vector-memory pipe for the 1 KB row traffic).
        const int nfu = __builtin_amdgcn_readfirstlane(nf0 + i);
        const int c   = ftc[nfu];
        const vf4 v   = xb[(size_t)c * ROW_F4];
        ob[(size_t)i * ROW_F4] = v;
    }
}

extern "C" void kernel_launch(void* const* d_in, const int* in_sizes, int n_in,
                              void* d_out, int out_size, void* d_ws, size_t ws_size,
                              hipStream_t stream) {
    const vf4* x   = (const vf4*)d_in[0];
    const int* ftc = (const int*)d_in[1];
    vf4*       out = (vf4*)d_out;

    dim3 grid(BLOCKS_X, B_);
    dim3 block(TPB);
    unpool_gather_kernel<<<grid, block, 0, stream>>>(x, ftc, out);
}

// Round 5
// 45.260 us; speedup vs baseline: 1.1361x; 1.1141x over previous
//
#include <hip/hip_runtime.h>
#include <hip/hip_bf16.h>

// Problem constants (from reference setup_inputs):
//   x: [B=4, NC=2000, F=4, H=64] fp32          (8.2 MB  — cache-resident)
//   fine_to_coarse: [NF=50000] int32 in [0,NC) (200 KB)
//   out: [B=4, NF=50000, F=4, H=64] fp32       (204.8 MB — write-BW bound)
// Row per (b,node) = F*H = 256 floats = 1 KB = 64 float4 = one wave.
//
// Round-1 structure (best so far: 45.6 us) with ONE change: 1024-thread
// blocks -> 12,500 WGs instead of 50,000. Theory: round 1 was WG
// launch/retire-rate limited (2.6 WG/cycle, 4 KB/WG -> 4.5 TB/s observed).

#define B_     4
#define NC_    2000
#define NF_    50000
#define ROW_F4 64
#define TPB    1024        // 16 waves/block, 16 rows/block

typedef float vf4 __attribute__((ext_vector_type(4)));

__global__ __launch_bounds__(TPB) void unpool_gather_kernel(
    const vf4* __restrict__ x,      // [B, NC, 64] vf4
    const int* __restrict__ ftc,    // [NF]
    vf4*       __restrict__ out)    // [B, NF, 64] vf4
{
    const int b   = blockIdx.y;
    const int idx = blockIdx.x * TPB + threadIdx.x;  // over NF_*64
    const int nf    = idx >> 6;        // wave-uniform (64 lanes per row)
    const int inner = idx & 63;

    const int c = ftc[nf];             // broadcast load within the wave

    const vf4 v = x[((size_t)b * NC_ + c) * ROW_F4 + inner];
    out[((size_t)b * NF_ + nf) * ROW_F4 + inner] = v;
}

extern "C" void kernel_launch(void* const* d_in, const int* in_sizes, int n_in,
                              void* d_out, int out_size, void* d_ws, size_t ws_size,
                              hipStream_t stream) {
    const vf4* x   = (const vf4*)d_in[0];
    const int* ftc = (const int*)d_in[1];
    vf4*       out = (vf4*)d_out;

    // NF_*64 vf4 slots per batch; 1024 threads/block -> 3125 blocks per b.
    dim3 grid((NF_ * 64) / TPB, B_);
    dim3 block(TPB);
    unpool_gather_kernel<<<grid, block, 0, stream>>>(x, ftc, out);
}

// Round 6
// 42.165 us; speedup vs baseline: 1.2195x; 1.0734x over previous
//
#include <hip/hip_runtime.h>
#include <hip/hip_bf16.h>

// Problem constants (from reference setup_inputs):
//   x: [B=4, NC=2000, F=4, H=64] fp32          (8.2 MB; 2 MB per batch slice)
//   fine_to_coarse: [NF=50000] int32 in [0,NC) (200 KB)
//   out: [B=4, NF=50000, F=4, H=64] fp32       (204.8 MB — write-BW bound)
// Row per (b,node) = F*H = 256 floats = 1 KB = 64 float4 = one wave.
//
// Round-1 structure (best: 45.3-45.6 us). Single change this round:
// nontemporal (write-around) stores for out, so the 205 MB write stream
// doesn't evict x[b] from L2 (gather reads stay L2-resident).

#define B_     4
#define NC_    2000
#define NF_    50000
#define ROW_F4 64
#define TPB    1024        // 16 waves/block (round 5: same perf as 256)

typedef float vf4 __attribute__((ext_vector_type(4)));

__global__ __launch_bounds__(TPB) void unpool_gather_kernel(
    const vf4* __restrict__ x,      // [B, NC, 64] vf4
    const int* __restrict__ ftc,    // [NF]
    vf4*       __restrict__ out)    // [B, NF, 64] vf4
{
    const int b   = blockIdx.y;
    const int idx = blockIdx.x * TPB + threadIdx.x;  // over NF_*64
    const int nf    = idx >> 6;        // wave-uniform (64 lanes per row)
    const int inner = idx & 63;

    const int c = ftc[nf];             // broadcast load within the wave

    const vf4 v = x[((size_t)b * NC_ + c) * ROW_F4 + inner];
    __builtin_nontemporal_store(v, &out[((size_t)b * NF_ + nf) * ROW_F4 + inner]);
}

extern "C" void kernel_launch(void* const* d_in, const int* in_sizes, int n_in,
                              void* d_out, int out_size, void* d_ws, size_t ws_size,
                              hipStream_t stream) {
    const vf4* x   = (const vf4*)d_in[0];
    const int* ftc = (const int*)d_in[1];
    vf4*       out = (vf4*)d_out;

    dim3 grid((NF_ * 64) / TPB, B_);
    dim3 block(TPB);
    unpool_gather_kernel<<<grid, block, 0, stream>>>(x, ftc, out);
}